// Round 6
// baseline (486.555 us; speedup 1.0000x reference)
//
#include <hip/hip_runtime.h>
#include <math.h>

#define NROWS  65536   // 16*64*64 rows
#define D      64
#define K      1024
#define KSPLIT 8
#define KPER   (K / KSPLIT)   // 128 codes per block
#define BETA   0.25f

// ---------------------------------------------------------------- enorm ----
__global__ __launch_bounds__(256) void vq_enorm(const float* __restrict__ emb,
                                                float* __restrict__ enorm) {
    int k = blockIdx.x * 256 + threadIdx.x;
    if (k >= K) return;
    const float4* e4 = (const float4*)(emb + (size_t)k * D);
    float s = 0.f;
    #pragma unroll
    for (int i = 0; i < 16; ++i) {
        float4 e = e4[i];
        s += e.x * e.x + e.y * e.y + e.z * e.z + e.w * e.w;
    }
    enorm[k] = s;
}

// ----------------------------------------------------------------- main ----
// R5 finding: s_load path is K$-MSHR-bound (shared cache thrash) -- adding
// waves gained ~0 (occ 41->47%, VALUBusy 40->45%). Fix: force the broadcast
// codebook loads onto the VMEM path (per-CU 32KB L1 exactly holds this
// block's 32KB slice; identical lane addresses coalesce to one L1 request;
// vmcnt pipelining is deep and VGPR-fed, no SGPR ceiling). The opaque zero
// VGPR below stops the compiler from proving the address uniform (which is
// what produced s_load in R3-R5).
__global__ __launch_bounds__(256, 4) void vq_main(const float* __restrict__ x,
                                                  const float* __restrict__ emb,
                                                  const float* __restrict__ enorm,
                                                  unsigned long long* __restrict__ cand) {
    const int tid = threadIdx.x;
    const int gb  = blockIdx.x >> 3;      // row group
    const int kq  = blockIdx.x & 7;       // codebook slice (== XCD id mod 8)
    const int n   = gb * 256 + tid;
    const int kbase0 = kq * KPER;

    // row of x into registers (16 x float4)
    float4 xr[16];
    const float4* xp = (const float4*)(x + (size_t)n * D);
    #pragma unroll
    for (int i = 0; i < 16; ++i) xr[i] = xp[i];

    float xnorm = 0.f;
    #pragma unroll
    for (int i = 0; i < 16; ++i) {
        float4 v = xr[i];
        xnorm += v.x * v.x + v.y * v.y + v.z * v.z + v.w * v.w;
    }

    float best = 3.4e38f;
    int   bidx = kbase0;

    // opaque zero in a VGPR: compiler cannot prove the e-address uniform,
    // so e-loads become global_load (VMEM/L1) instead of s_load (K$).
    int zero;
    asm volatile("v_mov_b32 %0, 0" : "=v"(zero));

    const float4* ebase = (const float4*)(emb + (size_t)kbase0 * D) + zero;
    const float*  enb   = enorm + kbase0;

    for (int kk = 0; kk < KPER; ++kk) {
        const float4* e4 = ebase + kk * (D / 4);   // VGPR-based broadcast addr
        float d0 = 0.f, d1 = 0.f, d2 = 0.f, d3 = 0.f;
        #pragma unroll
        for (int i = 0; i < 4; ++i) {
            float4 ea = e4[i * 4 + 0], eb = e4[i * 4 + 1];
            float4 ec = e4[i * 4 + 2], ed = e4[i * 4 + 3];
            float4 va = xr[i * 4 + 0], vb = xr[i * 4 + 1];
            float4 vc = xr[i * 4 + 2], vd = xr[i * 4 + 3];
            d0 = fmaf(va.w, ea.w, fmaf(va.z, ea.z, fmaf(va.y, ea.y, fmaf(va.x, ea.x, d0))));
            d1 = fmaf(vb.w, eb.w, fmaf(vb.z, eb.z, fmaf(vb.y, eb.y, fmaf(vb.x, eb.x, d1))));
            d2 = fmaf(vc.w, ec.w, fmaf(vc.z, ec.z, fmaf(vc.y, ec.y, fmaf(vc.x, ec.x, d2))));
            d3 = fmaf(vd.w, ed.w, fmaf(vd.z, ed.z, fmaf(vd.y, ed.y, fmaf(vd.x, ed.x, d3))));
        }
        float dot  = (d0 + d1) + (d2 + d3);
        // single-rounding form; same argmin decisions as verified round-1
        float dist = fmaf(-2.f, dot, xnorm + enb[kk]);
        if (dist < best) { best = dist; bidx = kbase0 + kk; }  // strict <
    }

    // pack (orderable-dist, idx) so uint64 min == (min dist, then min idx)
    unsigned int b = __float_as_uint(best);
    unsigned int u = (b & 0x80000000u) ? ~b : (b | 0x80000000u);
    cand[(size_t)kq * NROWS + n] = ((unsigned long long)u << 32) | (unsigned int)bidx;
}

// ------------------------------------------------- combine + gather + loss --
__global__ __launch_bounds__(256) void vq_combine(const float* __restrict__ x,
                                                  const float* __restrict__ emb,
                                                  const unsigned long long* __restrict__ cand,
                                                  float* __restrict__ out,
                                                  float* __restrict__ partial) {
    __shared__ int   lds_idx[256];
    __shared__ float lds_red[256];

    const int tid   = threadIdx.x;
    const int rbase = blockIdx.x * 256;
    const int n     = rbase + tid;

    unsigned long long m = cand[n];
    #pragma unroll
    for (int s = 1; s < KSPLIT; ++s) {
        unsigned long long c = cand[(size_t)s * NROWS + n];
        if (c < m) m = c;
    }
    lds_idx[tid] = (int)(unsigned int)(m & 0xFFFFFFFFu);
    __syncthreads();

    // 256 rows x 16 float4, 16 lanes per row: coalesced x/out, L2 gather of emb
    const float4* x4 = (const float4*)x;
    const float4* e4 = (const float4*)emb;
    float4* o4 = (float4*)out;
    float err = 0.f;
    #pragma unroll
    for (int i = 0; i < 16; ++i) {
        int f   = i * 256 + tid;          // flat float4 id within block
        int row = f >> 4;
        int col = f & 15;
        int e   = lds_idx[row];
        float4 q = e4[(size_t)e * 16 + col];
        float4 v = x4[(size_t)rbase * 16 + f];
        float ax = q.x - v.x, ay = q.y - v.y, az = q.z - v.z, aw = q.w - v.w;
        err += ax * ax + ay * ay + az * az + aw * aw;
        o4[(size_t)rbase * 16 + f] = q;
    }

    // deterministic block reduction of err
    __syncthreads();
    lds_red[tid] = err;
    __syncthreads();
    for (int s = 128; s > 0; s >>= 1) {
        if (tid < s) lds_red[tid] += lds_red[tid + s];
        __syncthreads();
    }
    if (tid == 0) partial[blockIdx.x] = lds_red[0];
}

// ------------------------------------------------------------- finalize ----
__global__ __launch_bounds__(256) void vq_finish(const float* __restrict__ partial,
                                                 float* __restrict__ loss_out) {
    __shared__ float lds[256];
    int tid = threadIdx.x;
    lds[tid] = partial[tid];
    __syncthreads();
    for (int s = 128; s > 0; s >>= 1) {
        if (tid < s) lds[tid] += lds[tid + s];
        __syncthreads();
    }
    // loss = codebook + BETA*commitment = (1+BETA) * mean((q-x)^2)
    if (tid == 0) loss_out[0] = (1.0f + BETA) * lds[0] / (float)(NROWS * D);
}

// ---------------------------------------------------------------- launch ---
extern "C" void kernel_launch(void* const* d_in, const int* in_sizes, int n_in,
                              void* d_out, int out_size, void* d_ws, size_t ws_size,
                              hipStream_t stream) {
    const float* x   = (const float*)d_in[0];
    const float* emb = (const float*)d_in[1];
    float* out = (float*)d_out;

    float* enorm = (float*)d_ws;                              // K floats
    float* partial = enorm + K;                               // 256 floats
    unsigned long long* cand =
        (unsigned long long*)((char*)d_ws + 8192);            // KSPLIT*NROWS u64 = 4 MB

    vq_enorm<<<K / 256, 256, 0, stream>>>(emb, enorm);
    vq_main<<<(NROWS / 256) * KSPLIT, 256, 0, stream>>>(x, emb, enorm, cand);
    vq_combine<<<NROWS / 256, 256, 0, stream>>>(x, emb, cand, out, partial);
    vq_finish<<<1, 256, 0, stream>>>(partial, out + (size_t)NROWS * D);
}

// Round 7
// 157.269 us; speedup vs baseline: 3.0938x; 3.0938x over previous
//
#include <hip/hip_runtime.h>
#include <math.h>

#define NROWS  65536   // 16*64*64 rows
#define D      64
#define K      1024
#define KSPLIT 8
#define KPER   (K / KSPLIT)   // 128 codes per block
#define ROWS2  512            // rows per block (2 per thread)
#define BETA   0.25f

// ---------------------------------------------------------------- enorm ----
__global__ __launch_bounds__(256) void vq_enorm(const float* __restrict__ emb,
                                                float* __restrict__ enorm) {
    int k = blockIdx.x * 256 + threadIdx.x;
    if (k >= K) return;
    const float4* e4 = (const float4*)(emb + (size_t)k * D);
    float s = 0.f;
    #pragma unroll
    for (int i = 0; i < 16; ++i) {
        float4 e = e4[i];
        s += e.x * e.x + e.y * e.y + e.z * e.z + e.w * e.w;
    }
    enorm[k] = s;
}

// ----------------------------------------------------------------- main ----
// Scalar-path (s_load) codebook broadcast -- measured supply ~2.6 B/cyc/CU
// (K$ MSHR-bound; R3->R5 showed waves don't raise it, R6 showed the vector
// path is 3x worse: per-lane broadcast return BW). So halve DEMAND instead:
// 2 x-rows per thread -> each fetched e-row serves 128 dots, scalar bytes
// 268->134 MB. VGPR ~150 (2x16 float4 + 8 acc) -> launch_bounds(256,2):
// cap 256, NO spill (R4: capping below the live set cost 3.4x).
__global__ __launch_bounds__(256, 2) void vq_main(const float* __restrict__ x,
                                                  const float* __restrict__ emb,
                                                  const float* __restrict__ enorm,
                                                  unsigned long long* __restrict__ cand) {
    const int tid = threadIdx.x;
    const int gb  = blockIdx.x >> 3;      // row group (512 rows)
    const int kq  = blockIdx.x & 7;       // codebook slice
    const int n0  = gb * ROWS2 + tid;
    const int n1  = n0 + 256;
    const int kbase0 = kq * KPER;

    // two rows of x into registers (2 x 16 float4 = 128 VGPRs)
    float4 xa[16], xb[16];
    const float4* xp0 = (const float4*)(x + (size_t)n0 * D);
    const float4* xp1 = (const float4*)(x + (size_t)n1 * D);
    #pragma unroll
    for (int i = 0; i < 16; ++i) { xa[i] = xp0[i]; xb[i] = xp1[i]; }

    float xn0 = 0.f, xn1 = 0.f;
    #pragma unroll
    for (int i = 0; i < 16; ++i) {
        float4 a = xa[i], b = xb[i];
        xn0 += a.x * a.x + a.y * a.y + a.z * a.z + a.w * a.w;
        xn1 += b.x * b.x + b.y * b.y + b.z * b.z + b.w * b.w;
    }

    float best0 = 3.4e38f, best1 = 3.4e38f;
    int   bidx0 = kbase0,  bidx1 = kbase0;

    const float4* ebase = (const float4*)(emb + (size_t)kbase0 * D);
    const float*  enb   = enorm + kbase0;

    #pragma unroll 2
    for (int kk = 0; kk < KPER; ++kk) {
        const float4* e4 = ebase + kk * (D / 4);   // uniform address -> s_load
        // 4 accumulator chains per row; identical per-dot FMA ordering to the
        // verified kernel -> identical argmin decisions.
        float p0 = 0.f, p1 = 0.f, p2 = 0.f, p3 = 0.f;
        float q0 = 0.f, q1 = 0.f, q2 = 0.f, q3 = 0.f;
        #pragma unroll
        for (int i = 0; i < 4; ++i) {
            float4 ea = e4[i * 4 + 0], eb = e4[i * 4 + 1];
            float4 ec = e4[i * 4 + 2], ed = e4[i * 4 + 3];
            float4 va = xa[i * 4 + 0], vb = xa[i * 4 + 1];
            float4 vc = xa[i * 4 + 2], vd = xa[i * 4 + 3];
            p0 = fmaf(va.w, ea.w, fmaf(va.z, ea.z, fmaf(va.y, ea.y, fmaf(va.x, ea.x, p0))));
            p1 = fmaf(vb.w, eb.w, fmaf(vb.z, eb.z, fmaf(vb.y, eb.y, fmaf(vb.x, eb.x, p1))));
            p2 = fmaf(vc.w, ec.w, fmaf(vc.z, ec.z, fmaf(vc.y, ec.y, fmaf(vc.x, ec.x, p2))));
            p3 = fmaf(vd.w, ed.w, fmaf(vd.z, ed.z, fmaf(vd.y, ed.y, fmaf(vd.x, ed.x, p3))));
            float4 wa = xb[i * 4 + 0], wb = xb[i * 4 + 1];
            float4 wc = xb[i * 4 + 2], wd = xb[i * 4 + 3];
            q0 = fmaf(wa.w, ea.w, fmaf(wa.z, ea.z, fmaf(wa.y, ea.y, fmaf(wa.x, ea.x, q0))));
            q1 = fmaf(wb.w, eb.w, fmaf(wb.z, eb.z, fmaf(wb.y, eb.y, fmaf(wb.x, eb.x, q1))));
            q2 = fmaf(wc.w, ec.w, fmaf(wc.z, ec.z, fmaf(wc.y, ec.y, fmaf(wc.x, ec.x, q2))));
            q3 = fmaf(wd.w, ed.w, fmaf(wd.z, ed.z, fmaf(wd.y, ed.y, fmaf(wd.x, ed.x, q3))));
        }
        float en   = enb[kk];
        float dot0 = (p0 + p1) + (p2 + p3);
        float dot1 = (q0 + q1) + (q2 + q3);
        float dist0 = fmaf(-2.f, dot0, xn0 + en);
        float dist1 = fmaf(-2.f, dot1, xn1 + en);
        if (dist0 < best0) { best0 = dist0; bidx0 = kbase0 + kk; }
        if (dist1 < best1) { best1 = dist1; bidx1 = kbase0 + kk; }
    }

    // pack (orderable-dist, idx) so uint64 min == (min dist, then min idx)
    unsigned int b0 = __float_as_uint(best0);
    unsigned int u0 = (b0 & 0x80000000u) ? ~b0 : (b0 | 0x80000000u);
    cand[(size_t)kq * NROWS + n0] = ((unsigned long long)u0 << 32) | (unsigned int)bidx0;
    unsigned int b1 = __float_as_uint(best1);
    unsigned int u1 = (b1 & 0x80000000u) ? ~b1 : (b1 | 0x80000000u);
    cand[(size_t)kq * NROWS + n1] = ((unsigned long long)u1 << 32) | (unsigned int)bidx1;
}

// ------------------------------------------------- combine + gather + loss --
__global__ __launch_bounds__(256) void vq_combine(const float* __restrict__ x,
                                                  const float* __restrict__ emb,
                                                  const unsigned long long* __restrict__ cand,
                                                  float* __restrict__ out,
                                                  float* __restrict__ partial) {
    __shared__ int   lds_idx[256];
    __shared__ float lds_red[256];

    const int tid   = threadIdx.x;
    const int rbase = blockIdx.x * 256;
    const int n     = rbase + tid;

    unsigned long long m = cand[n];
    #pragma unroll
    for (int s = 1; s < KSPLIT; ++s) {
        unsigned long long c = cand[(size_t)s * NROWS + n];
        if (c < m) m = c;
    }
    lds_idx[tid] = (int)(unsigned int)(m & 0xFFFFFFFFu);
    __syncthreads();

    // 256 rows x 16 float4, 16 lanes per row: coalesced x/out, L2 gather of emb
    const float4* x4 = (const float4*)x;
    const float4* e4 = (const float4*)emb;
    float4* o4 = (float4*)out;
    float err = 0.f;
    #pragma unroll
    for (int i = 0; i < 16; ++i) {
        int f   = i * 256 + tid;          // flat float4 id within block
        int row = f >> 4;
        int col = f & 15;
        int e   = lds_idx[row];
        float4 q = e4[(size_t)e * 16 + col];
        float4 v = x4[(size_t)rbase * 16 + f];
        float ax = q.x - v.x, ay = q.y - v.y, az = q.z - v.z, aw = q.w - v.w;
        err += ax * ax + ay * ay + az * az + aw * aw;
        o4[(size_t)rbase * 16 + f] = q;
    }

    // deterministic block reduction of err
    __syncthreads();
    lds_red[tid] = err;
    __syncthreads();
    for (int s = 128; s > 0; s >>= 1) {
        if (tid < s) lds_red[tid] += lds_red[tid + s];
        __syncthreads();
    }
    if (tid == 0) partial[blockIdx.x] = lds_red[0];
}

// ------------------------------------------------------------- finalize ----
__global__ __launch_bounds__(256) void vq_finish(const float* __restrict__ partial,
                                                 float* __restrict__ loss_out) {
    __shared__ float lds[256];
    int tid = threadIdx.x;
    lds[tid] = partial[tid];
    __syncthreads();
    for (int s = 128; s > 0; s >>= 1) {
        if (tid < s) lds[tid] += lds[tid + s];
        __syncthreads();
    }
    // loss = codebook + BETA*commitment = (1+BETA) * mean((q-x)^2)
    if (tid == 0) loss_out[0] = (1.0f + BETA) * lds[0] / (float)(NROWS * D);
}

// ---------------------------------------------------------------- launch ---
extern "C" void kernel_launch(void* const* d_in, const int* in_sizes, int n_in,
                              void* d_out, int out_size, void* d_ws, size_t ws_size,
                              hipStream_t stream) {
    const float* x   = (const float*)d_in[0];
    const float* emb = (const float*)d_in[1];
    float* out = (float*)d_out;

    float* enorm = (float*)d_ws;                              // K floats
    float* partial = enorm + K;                               // 256 floats
    unsigned long long* cand =
        (unsigned long long*)((char*)d_ws + 8192);            // KSPLIT*NROWS u64 = 4 MB

    vq_enorm<<<K / 256, 256, 0, stream>>>(emb, enorm);
    vq_main<<<(NROWS / ROWS2) * KSPLIT, 256, 0, stream>>>(x, emb, enorm, cand);
    vq_combine<<<NROWS / 256, 256, 0, stream>>>(x, emb, cand, out, partial);
    vq_finish<<<1, 256, 0, stream>>>(partial, out + (size_t)NROWS * D);
}